// Round 12
// baseline (687.609 us; speedup 1.0000x reference)
//
#include <hip/hip_runtime.h>
#include <stdint.h>

#define BATCH 16
#define H 512
#define W 512
#define HW (H * W)
#define NTOT (BATCH * HW)
#define NWORDS (NTOT / 64)
#define IMGW 4096                   // words per image (8 per row, 512 rows)
#define IMGQ 65536                  // float4 quads per image
#define SROWS 16                    // CCL strip = 16 rows
#define SWORDS 128                  // words per strip
#define MAXR 4096                   // max runs per strip
#define NR (BATCH * 32 * MAXR)      // rid space (8 MB per int array)
#define WALK_LIMIT (1 << 16)        // UF guard: corruption -> wrong answer, not hang

// ---------------------------------------------------------------------------
// ONE BLOCK PER IMAGE (r12). All cross-thread data is block-private =>
// workgroup scope everywhere: plain cached loads/stores for ordinary data
// (L1 write-through, single CU), workgroup-scope atomics executed at the
// local XCD L2. No agent-scope (sc1/MALL) traffic, no cross-block barriers —
// the invariant shared by five consecutive ~140us-pinned rounds (r6-r11).
// ---------------------------------------------------------------------------
static __device__ __forceinline__ int aldw(const int* p) {
    return __hip_atomic_load((int*)p, __ATOMIC_RELAXED, __HIP_MEMORY_SCOPE_WORKGROUP);
}
static __device__ __forceinline__ int aminw(int* p, int v) {
    return __hip_atomic_fetch_min(p, v, __ATOMIC_RELAXED, __HIP_MEMORY_SCOPE_WORKGROUP);
}
static __device__ __forceinline__ int aaddw(int* p, int v) {
    return __hip_atomic_fetch_add(p, v, __ATOMIC_RELAXED, __HIP_MEMORY_SCOPE_WORKGROUP);
}

// Union-find over run ids (block-private; atomicMin keeps parent<=child).
static __device__ __forceinline__ int find_root(int* L, int x) {
    int r = x, p = aldw(&L[r]), g = 0;
    while (p != r && ++g < WALK_LIMIT) { r = p; p = aldw(&L[r]); }
    if (aldw(&L[x]) != r) aminw(&L[x], r);
    return r;
}

static __device__ void merge_uf(int* L, int a, int b) {
    int g = 0;
    while (++g < WALK_LIMIT) {
        a = find_root(L, a);
        b = find_root(L, b);
        if (a == b) return;
        int lo = a < b ? a : b;
        int hi = a < b ? b : a;
        int old = aminw(&L[hi], lo);
        if (old == hi) return;
        a = lo; b = old;
    }
}

// rid of run containing bit i of word m; cvrid = rid continuing in (or -1),
// wr = rid of the word's first NEW run. (global-rid variant)
static __device__ __forceinline__ int run_of(uint64_t m, int i, int cvrid, int wr) {
    uint64_t below = i ? ((~m) & ((1ull << i) - 1)) : 0ull;
    if (below == 0) return (cvrid >= 0) ? cvrid : wr;
    int s = 64 - __builtin_clzll(below);
    uint64_t starts = m & ~((m << 1) | ((cvrid >= 0) ? 1ull : 0ull));
    return wr + __popcll(starts & ((1ull << s) - 1));
}

// local-rid variant (cv, wb local; starts precomputed)
static __device__ __forceinline__ int run_of_l(uint64_t m, int i, int cv,
                                               uint64_t starts, int wb) {
    uint64_t below = i ? ((~m) & ((1ull << i) - 1)) : 0ull;
    if (below == 0) return (cv >= 0) ? cv : wb;
    int s = 64 - __builtin_clzll(below);
    return wb + __popcll(starts & ((1ull << s) - 1));
}

// remove-small transform of one word (L compressed to depth-0 by flatten)
static __device__ uint64_t keep_word_g(uint64_t m, int cvg, int wrg,
                                       const int* L, const int* S, int minsz) {
    uint64_t res = m, rem = m; int rk = 0;
    while (rem) {
        int s = __builtin_ctzll(rem);
        uint64_t rest = rem >> s;
        uint64_t nr = ~rest;
        int len = nr ? __builtin_ctzll(nr) : (64 - s);
        uint64_t piece = ((len >= 64) ? ~0ull : ((1ull << len) - 1)) << s;
        bool ini = !(s == 0 && cvg >= 0);
        int rid = ini ? (wrg + rk) : cvg; rk += ini ? 1 : 0;
        if (aldw(&S[aldw(&L[rid])]) < minsz) res &= ~piece;
        rem &= ~piece;
    }
    return res;
}

// fill-holes transform of one word (bg rid space)
static __device__ uint64_t fill_word_g(uint64_t fg, int cvg, int wrg,
                                       const int* L, const int* S, int minsz) {
    uint64_t res = fg, rem = ~fg; int rk = 0;
    while (rem) {
        int s = __builtin_ctzll(rem);
        uint64_t rest = rem >> s;
        uint64_t nr = ~rest;
        int len = nr ? __builtin_ctzll(nr) : (64 - s);
        uint64_t piece = ((len >= 64) ? ~0ull : ((1ull << len) - 1)) << s;
        bool ini = !(s == 0 && cvg >= 0);
        int rid = ini ? (wrg + rk) : cvg; rk += ini ? 1 : 0;
        if (aldw(&S[aldw(&L[rid])]) < minsz) res |= piece;
        rem &= ~piece;
    }
    return res;
}

// one morph output word, reading the image bitmap from (cached) global
template <int R, bool ERODE>
static __device__ uint64_t morph_word_g(const uint64_t* ib, int row, int w) {
    const uint64_t BORDER = ERODE ? ~0ull : 0ull;
    uint64_t res = ERODE ? ~0ull : 0ull;
#pragma unroll
    for (int dy = -R; dy <= R; ++dy) {
        int gy = row + dy;
        if (gy < 0 || gy >= H) continue;       // image border rows = identity
        int v = R * R - dy * dy;
        int kx = 0;
        while ((kx + 1) * (kx + 1) <= v) ++kx;
        uint64_t cur = ib[gy * 8 + w];
        uint64_t prv = (w > 0) ? ib[gy * 8 + w - 1] : BORDER;
        uint64_t nxt = (w < 7) ? ib[gy * 8 + w + 1] : BORDER;
        uint64_t acc = cur;
#pragma unroll
        for (int dx = 1; dx <= kx; ++dx) {
            uint64_t right = (cur >> dx) | (nxt << (64 - dx));
            uint64_t left  = (cur << dx) | (prv >> (64 - dx));
            if (ERODE) acc &= right & left;
            else       acc |= right | left;
        }
        if (ERODE) res &= acc;
        else       res |= acc;
    }
    return res;
}

// ---------------------------------------------------------------------------
// Full-image CCL (one block, 1024 threads): 4 sub-rounds of 8 strips
// (sg = t>>7 picks strip, tt = t&127 word-in-strip), unions DIRECTLY in the
// global L array (block-private, cached), then cross-strip merges + flatten.
// ---------------------------------------------------------------------------
static __device__ void ccl_image(int img, int t, const uint64_t* bits, uint64_t inv64,
                                 int* carry, int* wordrun, int* L, int* S, int* ncomp,
                                 uint64_t (*ssw)[SWORDS], int (*sscar)[SWORDS],
                                 int (*scnt)[SWORDS], int (*swb)[SWORDS], int* wsum) {
    int sg = t >> 7, tt = t & 127;
    int lane = t & 63;
    if (t == 0) ncomp[img] = 0;

    for (int sr = 0; sr < 4; ++sr) {
        int si = sr * 8 + sg;
        int sid = img * 32 + si;
        int gb = sid * MAXR;
        int gw = sid * SWORDS + tt;            // == img*4096 + row*8 + w
        uint64_t m = bits[gw] ^ inv64;
        ssw[sg][tt] = m;
        __syncthreads();

        // per-word new-run count
        bool cont = (tt & 7) ? ((ssw[sg][tt - 1] >> 63) != 0) : false;
        int c = __popcll(m & ~(m << 1));
        if ((m & 1ull) && cont) --c;

        // inclusive scan over 128 words/strip: wave shfl scan + 1 LDS hop
        int x = c;
#pragma unroll
        for (int off = 1; off < 64; off <<= 1) {
            int y = __shfl_up(x, off);
            if (lane >= off) x += y;
        }
        if (tt == 63) wsum[sg] = x;            // strip's first-wave total
        __syncthreads();
        if (tt >= 64) x += wsum[sg];
        swb[sg][tt] = x;
        scnt[sg][tt] = c;
        __syncthreads();

        if (tt < SROWS) {                      // per-row rid carries (local)
            int cv = -1;
            for (int i = 0; i < 8; ++i) {
                int lw = tt * 8 + i;
                sscar[sg][lw] = cv;
                uint64_t w = ssw[sg][lw];
                if (w >> 63) { if (scnt[sg][lw] > 0) cv = swb[sg][lw] - 1; }
                else cv = -1;
            }
        }
        __syncthreads();

        int cv = sscar[sg][tt];
        int wb = swb[sg][tt] - scnt[sg][tt];   // exclusive base (local)
        carry[gw] = (cv >= 0) ? (gb + cv) : -1;
        wordrun[gw] = gb + wb;
        int nruns = swb[sg][127];
        for (int i = tt; i < nruns; i += 128) { L[gb + i] = gb + i; S[gb + i] = 0; }
        __syncthreads();                       // identity init visible to atomics

        if (tt >= 8 && m) {                    // intra-strip vertical unions
            uint64_t up = ssw[sg][tt - 8];
            uint64_t cand = m & up;
            if (cand) {
                uint64_t curprev = (tt & 7) ? ssw[sg][tt - 1] : 0ull;
                uint64_t upprev  = (tt & 7) ? ssw[sg][tt - 9] : 0ull;
                uint64_t curl = (m << 1) | (curprev >> 63);
                uint64_t upl  = (up << 1) | (upprev >> 63);
                cand &= ~(curl & upl);
                int cvu = sscar[sg][tt - 8];
                int wbu = swb[sg][tt - 8] - scnt[sg][tt - 8];
                uint64_t starts  = m & ~((m << 1) | ((cv >= 0) ? 1ull : 0ull));
                uint64_t startsU = up & ~((up << 1) | ((cvu >= 0) ? 1ull : 0ull));
                while (cand) {
                    int i = __builtin_ctzll(cand);
                    int sP = gb + run_of_l(m, i, cv, starts, wb);
                    int sQ = gb + run_of_l(up, i, cvu, startsU, wbu);
                    merge_uf(L, sP, sQ);
                    cand &= cand - 1;
                }
            }
        }
        __syncthreads();                       // before next sub-round reuses LDS
    }

    // cross-strip merges: 31 boundaries x 8 words, 4 threads per word
    if (t < 992) {
        int item = t >> 2, j = t & 3;          // item < 248
        int b = item >> 3, w = item & 7;       // boundary b: rows 16(b+1)-1 | 16(b+1)
        int gw = img * IMGW + (b + 1) * 128 + w;   // lower side (row 16(b+1))
        uint64_t cur = bits[gw] ^ inv64;
        uint64_t up  = bits[gw - 8] ^ inv64;
        uint64_t cand = cur & up;
        if (cand) {
            uint64_t curprev = w ? (bits[gw - 1] ^ inv64) : 0ull;
            uint64_t upprev  = w ? (bits[gw - 9] ^ inv64) : 0ull;
            uint64_t curl = (cur << 1) | (curprev >> 63);
            uint64_t upl  = (up << 1) | (upprev >> 63);
            cand &= ~(curl & upl);
            if (cand) {
                int cvc = carry[gw], wrc = wordrun[gw];
                int cvu = carry[gw - 8], wru = wordrun[gw - 8];
                int idx = 0;
                while (cand) {
                    int i = __builtin_ctzll(cand);
                    if ((idx & 3) == j) {
                        int sP = run_of(cur, i, cvc, wrc);
                        int sQ = run_of(up, i, cvu, wru);
                        merge_uf(L, sP, sQ);
                    }
                    ++idx;
                    cand &= cand - 1;
                }
            }
        }
    }
    __syncthreads();

    // flatten: path-compress every rid + accumulate sizes + exact ncomp
    for (int k = 0; k < 4; ++k) {
        int lw = t * 4 + k;
        int gw = img * IMGW + lw;
        uint64_t m = bits[gw] ^ inv64;
        if (!m) continue;
        int cvg = carry[gw], wrg = wordrun[gw];
        int rk = 0;
        uint64_t rem = m;
        while (rem) {
            int s = __builtin_ctzll(rem);
            uint64_t rest = rem >> s;
            uint64_t nr = ~rest;
            int len = nr ? __builtin_ctzll(nr) : (64 - s);
            uint64_t piece = ((len >= 64) ? ~0ull : ((1ull << len) - 1)) << s;
            bool ini = !(s == 0 && cvg >= 0);
            int rid = ini ? (wrg + rk) : cvg; rk += ini ? 1 : 0;
            int r = find_root(L, rid);         // compresses L[rid] -> root
            if (ini && r == rid) aaddw(&ncomp[img], 1);
            aaddw(&S[r], __popcll(piece));
            rem &= ~piece;
        }
    }
    __syncthreads();
}

// ---------------------------------------------------------------------------
// K_IMG: whole pipeline for one image per 1024-thread block. ~30 syncthreads,
// zero cross-block communication, zero agent-scope traffic.
// ---------------------------------------------------------------------------
__global__ __launch_bounds__(1024, 1) void k_img(
        const float4* __restrict__ in4, float* __restrict__ out,
        int* LA, int* SA, int* LB, int* SB,
        uint64_t* bits1, uint64_t* bits2, uint64_t* bits3,
        int* carryA, int* carryB, int* wrA, int* wrB,
        int* ncompA, int* ncompB) {
    __shared__ uint64_t ssw[8][SWORDS];        // 8 KB
    __shared__ int sscar[8][SWORDS];           // 4 KB
    __shared__ int scnt[8][SWORDS];            // 4 KB
    __shared__ int swb[8][SWORDS];             // 4 KB
    __shared__ int wsum[8];
    __shared__ int shnc;
    int img = blockIdx.x;
    int t = threadIdx.x;

    // P0: threshold + pack (coalesced float4 + 16-lane shfl nibble tree)
    for (int it = 0; it < 64; ++it) {
        int q = it * 1024 + t;                 // quad within image
        float4 v = in4[img * IMGQ + q];
        uint32_t nib = (v.x > 0.0f ? 1u : 0u) | (v.y > 0.0f ? 2u : 0u) |
                       (v.z > 0.0f ? 4u : 0u) | (v.w > 0.0f ? 8u : 0u);
        uint64_t val = (uint64_t)nib << (4 * (t & 15));
        val |= __shfl_xor(val, 1);
        val |= __shfl_xor(val, 2);
        val |= __shfl_xor(val, 4);
        val |= __shfl_xor(val, 8);
        if ((t & 15) == 0) bits1[img * IMGW + (q >> 4)] = val;
    }
    __syncthreads();

    // P1-P3: CCL1 (fg of bits1) -> set A
    ccl_image(img, t, bits1, 0ull, carryA, wrA, LA, SA, ncompA,
              ssw, sscar, scnt, swb, wsum);

    // P4: remove_small_objects(2000, guard) -> bits2
    if (t == 0) shnc = aldw(&ncompA[img]);
    __syncthreads();
    {
        int nc = shnc;
        for (int k = 0; k < 4; ++k) {
            int gw = img * IMGW + t * 4 + k;
            uint64_t m = bits1[gw];
            uint64_t kw = m;
            if (m && nc > 1)
                kw = keep_word_g(m, carryA[gw], wrA[gw], LA, SA, 2000);
            bits2[gw] = kw;
        }
    }
    __syncthreads();

    // P5: CCL2 (bg of bits2) -> set B
    ccl_image(img, t, bits2, ~0ull, carryB, wrB, LB, SB, ncompB,
              ssw, sscar, scnt, swb, wsum);

    // P6: fill_holes(<301): bits2 -> bits1
    for (int k = 0; k < 4; ++k) {
        int gw = img * IMGW + t * 4 + k;
        bits1[gw] = fill_word_g(bits2[gw], carryB[gw], wrB[gw], LB, SB, 301);
    }
    __syncthreads();

    // P7: erode(d2): bits1 -> bits2; erode(d5): bits2 -> bits1;
    //     dilate(d5): bits1 -> bits3   (full-image passes, L2-resident)
    {
        const uint64_t* ib = bits1 + img * IMGW;
        uint64_t* ob = bits2 + img * IMGW;
        for (int k = 0; k < 4; ++k) {
            int lw = t * 4 + k;
            ob[lw] = morph_word_g<2, true>(ib, lw >> 3, lw & 7);
        }
    }
    __syncthreads();
    {
        const uint64_t* ib = bits2 + img * IMGW;
        uint64_t* ob = bits1 + img * IMGW;
        for (int k = 0; k < 4; ++k) {
            int lw = t * 4 + k;
            ob[lw] = morph_word_g<5, true>(ib, lw >> 3, lw & 7);
        }
    }
    __syncthreads();
    {
        const uint64_t* ib = bits1 + img * IMGW;
        uint64_t* ob = bits3 + img * IMGW;
        for (int k = 0; k < 4; ++k) {
            int lw = t * 4 + k;
            ob[lw] = morph_word_g<5, false>(ib, lw >> 3, lw & 7);
        }
    }
    __syncthreads();

    // P8: CCL3 (fg of bits3) -> set A
    ccl_image(img, t, bits3, 0ull, carryA, wrA, LA, SA, ncompA,
              ssw, sscar, scnt, swb, wsum);

    // P9: remove_small_objects(2000, guard): bits3 -> bits1
    if (t == 0) shnc = aldw(&ncompA[img]);
    __syncthreads();
    {
        int nc = shnc;
        for (int k = 0; k < 4; ++k) {
            int gw = img * IMGW + t * 4 + k;
            uint64_t m = bits3[gw];
            uint64_t kw = m;
            if (m && nc > 1)
                kw = keep_word_g(m, carryA[gw], wrA[gw], LA, SA, 2000);
            bits1[gw] = kw;
        }
    }
    __syncthreads();

    // P10: dilate(disk1): bits1 -> bits2
    for (int k = 0; k < 4; ++k) {
        int lw = t * 4 + k;
        int row = lw >> 3, w = lw & 7;
        int gw = img * IMGW + lw;
        uint64_t cur = bits1[gw];
        uint64_t up  = row ? bits1[gw - 8] : 0ull;
        uint64_t dn  = (row < H - 1) ? bits1[gw + 8] : 0ull;
        uint64_t prv = w ? bits1[gw - 1] : 0ull;
        uint64_t nxt = (w < 7) ? bits1[gw + 1] : 0ull;
        bits2[gw] = cur | up | dn | (cur << 1) | (prv >> 63) |
                    (cur >> 1) | (nxt << 63);
    }
    __syncthreads();

    // P11: emit float32 (coalesced float4 stores)
    for (int it = 0; it < 64; ++it) {
        int q = it * 1024 + t;
        uint64_t d = bits2[img * IMGW + (q >> 4)];
        uint32_t nib = (uint32_t)(d >> ((q & 15) * 4)) & 0xFu;
        float4 f;
        f.x = (nib & 1u) ? 1.0f : 0.0f;
        f.y = (nib & 2u) ? 1.0f : 0.0f;
        f.z = (nib & 4u) ? 1.0f : 0.0f;
        f.w = (nib & 8u) ? 1.0f : 0.0f;
        ((float4*)out)[img * IMGQ + q] = f;
    }
}

// ---------------------------------------------------------------------------
// Host side — ONE dispatch, 16 blocks x 1024 threads
// ---------------------------------------------------------------------------
extern "C" void kernel_launch(void* const* d_in, const int* in_sizes, int n_in,
                              void* d_out, int out_size, void* d_ws, size_t ws_size,
                              hipStream_t stream) {
    const float* in = (const float*)d_in[0];
    float* out = (float*)d_out;

    uint8_t* ws = (uint8_t*)d_ws;
    int* LA      = (int*)ws;                                  // 8 MB (rid space)
    int* SA      = LA + NR;                                   // 8 MB
    int* LB      = SA + NR;                                   // 8 MB
    int* SB      = LB + NR;                                   // 8 MB
    uint64_t* bits1 = (uint64_t*)(SB + NR);                   // 512 KB
    uint64_t* bits2 = bits1 + NWORDS;                         // 512 KB
    uint64_t* bits3 = bits2 + NWORDS;                         // 512 KB
    int* carryA  = (int*)(bits3 + NWORDS);                    // 256 KB
    int* carryB  = carryA + NWORDS;                           // 256 KB
    int* wrA     = carryB + NWORDS;                           // 256 KB
    int* wrB     = wrA + NWORDS;                              // 256 KB
    int* ncompA  = wrB + NWORDS;                              // 64 B
    int* ncompB  = ncompA + BATCH;                            // 64 B

    k_img<<<BATCH, 1024, 0, stream>>>((const float4*)in, out,
                                      LA, SA, LB, SB,
                                      bits1, bits2, bits3,
                                      carryA, carryB, wrA, wrB,
                                      ncompA, ncompB);
}

// Round 13
// 187.519 us; speedup vs baseline: 3.6669x; 3.6669x over previous
//
#include <hip/hip_runtime.h>
#include <stdint.h>

#define BATCH 16
#define H 512
#define W 512
#define HW (H * W)
#define NTOT (BATCH * HW)
#define NWORDS (NTOT / 64)      // 65536 packed words, 8 per row, 4096 per image

#define SROWS 16                // CCL strip = 16 rows
#define SWORDS 128              // words per CCL strip
#define SPIX 8192               // pixels per CCL strip
#define NSTRIPS (NWORDS / SWORDS)   // 512 strips (never straddle images)
#define IMG_STRIPS 32               // strips per image

#define MAXR 4096                   // max runs per strip (128 words x 32)
#define NR (NSTRIPS * MAXR)         // run-id space: 2M ids, 8 MB per array

#define SPIN_LIMIT (1 << 20)        // hang-insurance: give up loudly, not hang

// ---------------------------------------------------------------------------
// Agent-scope relaxed accessors (sc1, coherence-point). Proven r3/r4: relaxed
// agent atomics are individually coherent across XCDs with NO fences. All
// cross-block workspace traffic goes through these; zero __threadfence in the
// kernel (r4: fence removal cut 269->135 us). This exact version measured
// 186.94 us total (best of 12 rounds); r5-r12 alternatives all null or worse.
// ---------------------------------------------------------------------------
__device__ __forceinline__ int ald(const int* p) {
    return __hip_atomic_load((int*)p, __ATOMIC_RELAXED, __HIP_MEMORY_SCOPE_AGENT);
}
__device__ __forceinline__ void ast(int* p, int v) {
    __hip_atomic_store(p, v, __ATOMIC_RELAXED, __HIP_MEMORY_SCOPE_AGENT);
}
__device__ __forceinline__ uint64_t ald64(const uint64_t* p) {
    return __hip_atomic_load((uint64_t*)p, __ATOMIC_RELAXED, __HIP_MEMORY_SCOPE_AGENT);
}
__device__ __forceinline__ void ast64(uint64_t* p, uint64_t v) {
    __hip_atomic_store(p, v, __ATOMIC_RELAXED, __HIP_MEMORY_SCOPE_AGENT);
}

// ---------------------------------------------------------------------------
// Union-find over run ids (global): atomicMin keeps parent <= child -> acyclic.
// ---------------------------------------------------------------------------
__device__ __forceinline__ int find_root_c(int* L, int x) {
    int r = x, p = ald(&L[r]);
    while (p != r) { r = p; p = ald(&L[r]); }
    if (ald(&L[x]) != r) atomicMin(&L[x], r);
    return r;
}

__device__ void merge_uf(int* L, int a, int b) {
    while (true) {
        a = find_root_c(L, a);
        b = find_root_c(L, b);
        if (a == b) return;
        int lo = a < b ? a : b;
        int hi = a < b ? b : a;
        int old = atomicMin(&L[hi], lo);
        if (old == hi) return;
        a = lo; b = old;
    }
}

__device__ __forceinline__ int find_root_lds(int* P, int x) {
    int r = x, p = P[r];
    while (p != r) { r = p; p = P[r]; }
    return r;
}

__device__ void merge_lds(int* P, int a, int b) {
    while (true) {
        a = find_root_lds(P, a);
        b = find_root_lds(P, b);
        if (a == b) return;
        int lo = a < b ? a : b;
        int hi = a < b ? b : a;
        int old = atomicMin(&P[hi], lo);
        if (old == hi) return;
        a = lo; b = old;
    }
}

// rid of the run containing bit i of word m; cvrid = global rid continuing in,
// wr = global rid of the word's first NEW run.
__device__ __forceinline__ int run_of(uint64_t m, int i, int cvrid, int wr) {
    uint64_t below = i ? ((~m) & ((1ull << i) - 1)) : 0ull;
    if (below == 0) return (cvrid >= 0) ? cvrid : wr;
    int s = 64 - __builtin_clzll(below);           // start bit of i's run
    uint64_t starts = m & ~((m << 1) | ((cvrid >= 0) ? 1ull : 0ull));
    return wr + __popcll(starts & ((1ull << s) - 1));
}

__device__ __forceinline__ int run_of_lds(uint64_t m, int i, int cvrid,
                                          uint64_t starts, int wb) {
    uint64_t below = i ? ((~m) & ((1ull << i) - 1)) : 0ull;
    if (below == 0) return (cvrid >= 0) ? cvrid : wb;
    int s = 64 - __builtin_clzll(below);
    return wb + __popcll(starts & ((1ull << s) - 1));
}

// remove-small transform of one word (fg comps; pure function of CCL data)
__device__ uint64_t keep_word(const uint64_t* __restrict__ bits,
                              const int* __restrict__ carry, const int* __restrict__ wordrun,
                              const int* __restrict__ L, const int* __restrict__ sizes,
                              const int* __restrict__ ncomp, int minsz, int gw) {
    uint64_t m = ald64(&bits[gw]);
    uint64_t res = m;
    if (m && ald(&ncomp[gw >> 12]) > 1) {
        int cv = ald(&carry[gw]);
        int wr = ald(&wordrun[gw]);
        int rk = 0;
        while (m) {
            int s = __builtin_ctzll(m);
            uint64_t rest = m >> s;
            uint64_t nr = ~rest;
            int len = nr ? __builtin_ctzll(nr) : (64 - s);
            uint64_t piece = ((len >= 64) ? ~0ull : ((1ull << len) - 1)) << s;
            bool initial = !(s == 0 && cv >= 0);
            int rid = initial ? (wr + rk++) : cv;
            if (ald(&sizes[ald(&L[rid])]) < minsz) res &= ~piece;
            m &= ~piece;
        }
    }
    return res;
}

// fill-holes transform of one word (bg comps; needs inv=1 CCL data)
__device__ uint64_t fill_word(const uint64_t* __restrict__ bits,
                              const int* __restrict__ carry, const int* __restrict__ wordrun,
                              const int* __restrict__ L, const int* __restrict__ sizes,
                              int minsz, int gw) {
    uint64_t fg = ald64(&bits[gw]);
    uint64_t bg = ~fg;
    uint64_t res = fg;
    int cv = ald(&carry[gw]);
    int wr = ald(&wordrun[gw]);
    int rk = 0;
    while (bg) {
        int s = __builtin_ctzll(bg);
        uint64_t rest = bg >> s;
        uint64_t nr = ~rest;
        int len = nr ? __builtin_ctzll(nr) : (64 - s);
        uint64_t piece = ((len >= 64) ? ~0ull : ((1ull << len) - 1)) << s;
        bool initial = !(s == 0 && cv >= 0);
        int rid = initial ? (wr + rk++) : cv;
        if (ald(&sizes[ald(&L[rid])]) < minsz) res |= piece;
        bg &= ~piece;
    }
    return res;
}

// one morph output word from an LDS window; gyTop = global row of local row 0
template <int R, bool ERODE>
__device__ uint64_t morph_word_lds(const uint64_t* buf, int lrow, int w, int gyTop) {
    const uint64_t BORDER = ERODE ? ~0ull : 0ull;
    uint64_t res = ERODE ? ~0ull : 0ull;
#pragma unroll
    for (int dy = -R; dy <= R; ++dy) {
        int lr = lrow + dy;
        int gy = gyTop + lr;
        if (gy < 0 || gy >= H) continue;       // image border rows = identity
        int v = R * R - dy * dy;
        int kx = 0;
        while ((kx + 1) * (kx + 1) <= v) ++kx;
        uint64_t cur = buf[lr * 8 + w];
        uint64_t prv = (w > 0) ? buf[lr * 8 + w - 1] : BORDER;
        uint64_t nxt = (w < 7) ? buf[lr * 8 + w + 1] : BORDER;
        uint64_t acc = cur;
#pragma unroll
        for (int dx = 1; dx <= kx; ++dx) {
            uint64_t right = (cur >> dx) | (nxt << (64 - dx));
            uint64_t left  = (cur << dx) | (prv >> (64 - dx));
            if (ERODE) acc &= right & left;
            else       acc |= right | left;
        }
        if (ERODE) res &= acc;
        else       res |= acc;
    }
    return res;
}

// ---------------------------------------------------------------------------
// Strip-local CCL body, RUN-ID edition (blockDim 256; t >= SWORDS pass m = 0).
// ---------------------------------------------------------------------------
__device__ void strip_ccl_body(uint64_t m, uint64_t* sw, int* scarry,
                               int* cntL, int* wbL, int* par,
                               int blk, int t,
                               int* __restrict__ carry, int* __restrict__ wordrun,
                               int* __restrict__ L, int* __restrict__ sizes,
                               int* __restrict__ ncomp) {
    if (t < SWORDS) sw[t] = m;
    __syncthreads();

    if (t < SWORDS) {                   // per-word new-run count
        bool cont = (t & 7) ? ((sw[t - 1] >> 63) != 0) : false;
        int c = __popcll(m & ~(m << 1));
        if ((m & 1ull) && cont) --c;
        cntL[t] = c;
        wbL[t] = c;
    }
    __syncthreads();
    for (int off = 1; off < SWORDS; off <<= 1) {   // inclusive scan (128)
        int v = 0;
        if (t < SWORDS && t >= off) v = wbL[t - off];
        __syncthreads();
        if (t < SWORDS) wbL[t] += v;
        __syncthreads();
    }

    if (t < SROWS) {                    // per-row rid carries
        int cv = -1;
        for (int i = 0; i < 8; ++i) {
            int lw = t * 8 + i;
            scarry[lw] = cv;
            uint64_t w = sw[lw];
            if (w >> 63) { if (cntL[lw] > 0) cv = wbL[lw] - 1; }  // last start's rid
            else cv = -1;
        }
    }
    for (int i = t; i < MAXR; i += 256) par[i] = i;   // identity init
    __syncthreads();

    int cv = -1, wb = 0;
    uint64_t starts = 0ull;
    if (t < SWORDS) {
        cv = scarry[t];
        wb = wbL[t] - cntL[t];          // exclusive base
        ast(&carry[blk * SWORDS + t], (cv >= 0) ? (blk * MAXR + cv) : -1);
        ast(&wordrun[blk * SWORDS + t], blk * MAXR + wb);
        starts = m & ~((m << 1) | ((cv >= 0) ? 1ull : 0ull));
    }
    __syncthreads();

    if (t >= 8 && t < SWORDS && m) {    // intra-strip vertical unions
        uint64_t up = sw[t - 8];
        uint64_t cand = m & up;
        if (cand) {
            uint64_t curprev = (t & 7) ? sw[t - 1] : 0ull;
            uint64_t upprev  = (t & 7) ? sw[t - 9] : 0ull;
            uint64_t curl = (m << 1) | (curprev >> 63);
            uint64_t upl  = (up << 1) | (upprev >> 63);
            cand &= ~(curl & upl);
            int cvu = scarry[t - 8];
            int wbu = wbL[t - 8] - cntL[t - 8];
            uint64_t startsU = up & ~((up << 1) | ((cvu >= 0) ? 1ull : 0ull));
            while (cand) {
                int i = __builtin_ctzll(cand);
                int sP = run_of_lds(m, i, cv, starts, wb);
                int sQ = run_of_lds(up, i, cvu, startsU, wbu);
                merge_lds(par, sP, sQ);
                cand &= cand - 1;
            }
        }
    }
    __syncthreads();

    if (t < SWORDS) {                   // publish depth-1 trees (rid space)
        int g = blk * MAXR;
        uint64_t ss = starts;
        int rk = 0;
        while (ss) {
            int rid = wb + rk; ++rk;
            int r = find_root_lds(par, rid);
            ast(&L[g + rid], g + r);
            if (r == rid) ast(&sizes[g + rid], 0);
            ss &= ss - 1;
        }
    }
    if (t == 0 && (blk & 31) == 0) ast(&ncomp[blk >> 5], 0);  // 32 strips/image
}

// one cross-strip boundary word (y % 16 == 0, y != 0)
__device__ void merge_bound_item(const uint64_t* __restrict__ bits, uint64_t inv64,
                                 const int* __restrict__ carry,
                                 const int* __restrict__ wordrun,
                                 int* __restrict__ L, int gw, int w) {
    uint64_t cur = ald64(&bits[gw]) ^ inv64;
    uint64_t up  = ald64(&bits[gw - 8]) ^ inv64;
    uint64_t cand = cur & up;
    if (!cand) return;
    uint64_t curprev = w ? (ald64(&bits[gw - 1]) ^ inv64) : 0ull;
    uint64_t upprev  = w ? (ald64(&bits[gw - 9]) ^ inv64) : 0ull;
    uint64_t curl = (cur << 1) | (curprev >> 63);
    uint64_t upl  = (up << 1)  | (upprev >> 63);
    cand &= ~(curl & upl);
    if (!cand) return;
    int cvc = ald(&carry[gw]), cvu = ald(&carry[gw - 8]);
    int wrc = ald(&wordrun[gw]), wru = ald(&wordrun[gw - 8]);
    while (cand) {
        int i = __builtin_ctzll(cand);
        int sP = run_of(cur, i, cvc, wrc);
        int sQ = run_of(up, i, cvu, wru);
        merge_uf(L, sP, sQ);
        cand &= cand - 1;
    }
}

// flatten+count for one strip's 128 words (per-block LDS hash, rid space)
__device__ void flatten_block(const uint64_t* __restrict__ bits, uint64_t inv64,
                              const int* __restrict__ carry,
                              const int* __restrict__ wordrun,
                              int* __restrict__ L,
                              int* __restrict__ sizes, int* __restrict__ ncomp,
                              int blk, int t, int* hk, int* hv) {
    if (t < 128) { hk[t] = -1; hv[t] = 0; }
    __syncthreads();
    if (t < SWORDS) {
        int gw = blk * SWORDS + t;
        uint64_t m = ald64(&bits[gw]) ^ inv64;
        if (m) {
            int cv = ald(&carry[gw]);
            int wr = ald(&wordrun[gw]);
            int rk = 0;
            while (m) {
                int s = __builtin_ctzll(m);
                uint64_t rest = m >> s;
                uint64_t nr = ~rest;
                int len = nr ? __builtin_ctzll(nr) : (64 - s);
                uint64_t piece = ((len >= 64) ? ~0ull : ((1ull << len) - 1)) << s;
                bool initial = !(s == 0 && cv >= 0);
                int rid = initial ? (wr + rk++) : cv;
                int r = find_root_c(L, rid);
                if (initial && r == rid) atomicAdd(&ncomp[gw >> 12], 1);
                int cnt = __popcll(piece);
                uint32_t h = ((uint32_t)r * 2654435761u) >> 25;
                bool done = false;
                for (int tt = 0; tt < 16; ++tt) {
                    int slot = (h + tt) & 127;
                    int k = hk[slot];
                    if (k == -1) k = atomicCAS(&hk[slot], -1, r);
                    if (k == -1 || k == r) { atomicAdd(&hv[slot], cnt); done = true; break; }
                }
                if (!done) atomicAdd(&sizes[r], cnt);
                m &= ~piece;
            }
        }
    }
    __syncthreads();
    if (t < 128 && hk[t] != -1) atomicAdd(&sizes[hk[t]], hv[t]);
}

// keep + dilate(disk1) + float4 cast for one 8-row segment (256 threads)
__device__ void keep_dilate_seg(const uint64_t* __restrict__ bits,
                                const int* __restrict__ carry,
                                const int* __restrict__ wordrun,
                                const int* __restrict__ L,
                                const int* __restrict__ sizes,
                                const int* __restrict__ ncomp,
                                float* __restrict__ out,
                                int img, int y0, int t, uint64_t* kb, uint64_t* db) {
    if (t < 80) {
        int lr = t >> 3;
        int w = t & 7;
        int gy = y0 - 1 + lr;
        uint64_t v = 0;
        if (gy >= 0 && gy < H)
            v = keep_word(bits, carry, wordrun, L, sizes, ncomp, 2000,
                          img * 4096 + gy * 8 + w);
        kb[t] = v;
    }
    __syncthreads();
    if (t < 64) {
        int r = t >> 3, w = t & 7;
        uint64_t cur = kb[(r + 1) * 8 + w];
        uint64_t up  = kb[r * 8 + w];
        uint64_t dn  = kb[(r + 2) * 8 + w];
        uint64_t prv = w ? kb[(r + 1) * 8 + w - 1] : 0ull;
        uint64_t nxt = (w < 7) ? kb[(r + 1) * 8 + w + 1] : 0ull;
        db[t] = cur | up | dn | (cur << 1) | (prv >> 63) | (cur >> 1) | (nxt << 63);
    }
    __syncthreads();

    int q0 = t * 16;                    // 16 consecutive pixels per thread
    uint64_t wd = db[q0 >> 6];
    int sh = q0 & 63;
    float4* o = (float4*)(out + (size_t)img * HW + (size_t)y0 * W + q0);
#pragma unroll
    for (int k = 0; k < 4; ++k) {
        uint32_t nib = (uint32_t)(wd >> (sh + k * 4)) & 0xFu;
        float4 f;
        f.x = (nib & 1u) ? 1.0f : 0.0f;
        f.y = (nib & 2u) ? 1.0f : 0.0f;
        f.z = (nib & 4u) ? 1.0f : 0.0f;
        f.w = (nib & 8u) ? 1.0f : 0.0f;
        o[k] = f;
    }
}

// ---------------------------------------------------------------------------
// PER-IMAGE fence-free barrier: sync only the 32 blocks of one image.
// Release = vmcnt(0) (sc1 stores ack'd at coherence point), arrival = own
// flag store, detection = 32 threads poll the image's 32 flags.
// ---------------------------------------------------------------------------
__device__ __forceinline__ void ibar(int* flags, int img, int si, int phase) {
    int* base = flags + img * 32;
    __syncthreads();
    if (threadIdx.x == 0) {
        asm volatile("s_waitcnt vmcnt(0)" ::: "memory");   // release: stores ack'd
        ast(&base[si], phase);
    }
    if (threadIdx.x < 32) {
        int spins = 0;
        while (ald(&base[threadIdx.x]) < phase && ++spins < SPIN_LIMIT)
            __builtin_amdgcn_s_sleep(1);
    }
    __syncthreads();
}

// ---------------------------------------------------------------------------
// MEGA: whole pipeline, ONE regular kernel, 9 per-image barriers, run-id UF.
// 512 blocks x 256 thr, ~18.6 KB LDS, __launch_bounds__(256,2).
// ---------------------------------------------------------------------------
__global__ __launch_bounds__(256, 2) void k_mega(
        const float4* __restrict__ in4, float* __restrict__ out,
        int* LA, int* sizesA, int* LB, int* sizesB,
        uint64_t* bits1, uint64_t* bits2, uint64_t* bits3,
        int* carryA, int* carryB, int* wordrunA, int* wordrunB,
        int* ncompA, int* ncompB, int* flags) {
    __shared__ uint64_t sw[SWORDS];
    __shared__ int scarry[SWORDS];
    __shared__ int cntL[SWORDS];
    __shared__ int wbL[SWORDS];
    __shared__ union US {
        int par[MAXR];                                     // 16 KB (CCL)
        struct { uint64_t A[320]; uint64_t B[320]; } mo;   // 5 KB (morph)
        struct { int hk[128]; int hv[128]; } ha;           // 1 KB (flatten hash)
        struct { uint64_t kb[80]; uint64_t db[64]; } kd;   // 1.1 KB (out stage)
    } U;
    int blk = blockIdx.x;
    int t = threadIdx.x;
    int img = blk >> 5, si = blk & 31;   // image id, strip-in-image

    // P0: threshold + pack, STRIP-LOCAL (block packs its own 128 words)
#pragma unroll
    for (int it = 0; it < 8; ++it) {
        int q = blk * (SPIX / 4) + it * 256 + t;           // quad index
        float4 v = in4[q];
        uint32_t nib = (v.x > 0.0f ? 1u : 0u) | (v.y > 0.0f ? 2u : 0u) |
                       (v.z > 0.0f ? 4u : 0u) | (v.w > 0.0f ? 8u : 0u);
        uint64_t val = (uint64_t)nib << (4 * (t & 15));
        val |= __shfl_xor(val, 1);
        val |= __shfl_xor(val, 2);
        val |= __shfl_xor(val, 4);
        val |= __shfl_xor(val, 8);
        if ((t & 15) == 0) ast64(&bits1[q >> 4], val);
    }
    __syncthreads();

    // P1: CCL1 strip phase (fg of bits1) -> set A
    {
        uint64_t m = (t < SWORDS) ? ald64(&bits1[blk * SWORDS + t]) : 0ull;
        strip_ccl_body(m, sw, scarry, cntL, wbL, U.par, blk, t,
                       carryA, wordrunA, LA, sizesA, ncompA);
    }
    ibar(flags, img, si, 1);

    // P2: cross-strip merges (bits1, fg) — image-local: 248 items / 32 blocks
    if (t < 8) {
        int item = si * 8 + t;
        if (item < 248) {
            int gw = img * 4096 + ((item >> 3) + 1) * SROWS * 8 + (item & 7);
            merge_bound_item(bits1, 0ull, carryA, wordrunA, LA, gw, item & 7);
        }
    }
    ibar(flags, img, si, 2);

    // P3: flatten + count (bits1, fg) -> sizesA, ncompA
    flatten_block(bits1, 0ull, carryA, wordrunA, LA, sizesA, ncompA,
                  blk, t, U.ha.hk, U.ha.hv);
    ibar(flags, img, si, 3);

    // P4: remove_small_objects(2000,guard) -> bits2, fused with CCL2 strip (bg)
    {
        uint64_t m = 0ull;
        if (t < SWORDS) {
            int gw = blk * SWORDS + t;
            uint64_t kw = keep_word(bits1, carryA, wordrunA, LA, sizesA, ncompA,
                                    2000, gw);
            ast64(&bits2[gw], kw);
            m = ~kw;
        }
        strip_ccl_body(m, sw, scarry, cntL, wbL, U.par, blk, t,
                       carryB, wordrunB, LB, sizesB, ncompB);
    }
    ibar(flags, img, si, 4);

    // P5: cross-strip merges (bits2, bg)
    if (t < 8) {
        int item = si * 8 + t;
        if (item < 248) {
            int gw = img * 4096 + ((item >> 3) + 1) * SROWS * 8 + (item & 7);
            merge_bound_item(bits2, ~0ull, carryB, wordrunB, LB, gw, item & 7);
        }
    }
    ibar(flags, img, si, 5);

    // P6: flatten + count (bits2, bg) -> sizesB
    flatten_block(bits2, ~0ull, carryB, wordrunB, LB, sizesB, ncompB,
                  blk, t, U.ha.hk, U.ha.hv);
    ibar(flags, img, si, 6);

    // P7: fill_holes(<301) + erode(d2) + opening(d5) + CCL3 strip -> bits3, A
    {
        int gyTop = si * 16 - 12;
        for (int lw = t; lw < 320; lw += 256) {              // load + fill-holes
            int gy = gyTop + (lw >> 3);
            int w = lw & 7;
            uint64_t v = 0;
            if (gy >= 0 && gy < H)
                v = fill_word(bits2, carryB, wordrunB, LB, sizesB, 301,
                              img * 4096 + gy * 8 + w);
            U.mo.A[lw] = v;
        }
        __syncthreads();
        for (int lw = t; lw < 320; lw += 256) {              // erode disk(2)
            int lr = lw >> 3;
            if (lr >= 2 && lr <= 37) U.mo.B[lw] = morph_word_lds<2, true>(U.mo.A, lr, lw & 7, gyTop);
        }
        __syncthreads();
        for (int lw = t; lw < 320; lw += 256) {              // erode disk(5)
            int lr = lw >> 3;
            if (lr >= 7 && lr <= 32) U.mo.A[lw] = morph_word_lds<5, true>(U.mo.B, lr, lw & 7, gyTop);
        }
        __syncthreads();
        for (int lw = t; lw < 320; lw += 256) {              // dilate disk(5)
            int lr = lw >> 3;
            if (lr >= 12 && lr <= 27) U.mo.B[lw] = morph_word_lds<5, false>(U.mo.A, lr, lw & 7, gyTop);
        }
        __syncthreads();
        uint64_t m3 = 0ull;
        if (t < SWORDS) {
            m3 = U.mo.B[t + 96];        // local rows 12..27 = this strip
            ast64(&bits3[blk * SWORDS + t], m3);
        }
        // par aliases mo — safe: all mo.B reads (m3) happen before body's first
        // par write, which is behind multiple __syncthreads
        strip_ccl_body(m3, sw, scarry, cntL, wbL, U.par, blk, t,
                       carryA, wordrunA, LA, sizesA, ncompA);
    }
    ibar(flags, img, si, 7);

    // P8: cross-strip merges (bits3, fg)
    if (t < 8) {
        int item = si * 8 + t;
        if (item < 248) {
            int gw = img * 4096 + ((item >> 3) + 1) * SROWS * 8 + (item & 7);
            merge_bound_item(bits3, 0ull, carryA, wordrunA, LA, gw, item & 7);
        }
    }
    ibar(flags, img, si, 8);

    // P9: flatten + count (bits3, fg) -> sizesA, ncompA
    flatten_block(bits3, 0ull, carryA, wordrunA, LA, sizesA, ncompA,
                  blk, t, U.ha.hk, U.ha.hv);
    ibar(flags, img, si, 9);

    // P10: remove_small_objects(2000,guard) + dilate(d1) + float4 out
    for (int k = 0; k < 2; ++k) {
        int seg = blk * 2 + k;          // seg>>6 == img by construction
        int s8 = seg & 63;
        keep_dilate_seg(bits3, carryA, wordrunA, LA, sizesA, ncompA, out,
                        img, s8 * 8, t, U.kd.kb, U.kd.db);
        __syncthreads();
    }
}

// ---------------------------------------------------------------------------
// Host side — memset(flags, 2 KB) + 1 regular dispatch
// ---------------------------------------------------------------------------
extern "C" void kernel_launch(void* const* d_in, const int* in_sizes, int n_in,
                              void* d_out, int out_size, void* d_ws, size_t ws_size,
                              hipStream_t stream) {
    const float* in = (const float*)d_in[0];
    float* out = (float*)d_out;

    uint8_t* ws = (uint8_t*)d_ws;
    int* LA      = (int*)ws;                                  // 8 MB (rid space)
    int* sizesA  = LA + NR;                                   // 8 MB
    int* LB      = sizesA + NR;                               // 8 MB
    int* sizesB  = LB + NR;                                   // 8 MB
    uint64_t* bits1 = (uint64_t*)(sizesB + NR);               // 512 KB
    uint64_t* bits2 = bits1 + NWORDS;                         // 512 KB
    uint64_t* bits3 = bits2 + NWORDS;                         // 512 KB
    int* carryA   = (int*)(bits3 + NWORDS);                   // 256 KB
    int* carryB   = carryA + NWORDS;                          // 256 KB
    int* wordrunA = carryB + NWORDS;                          // 256 KB
    int* wordrunB = wordrunA + NWORDS;                        // 256 KB
    int* ncompA   = wordrunB + NWORDS;                        // 64 B
    int* ncompB   = ncompA + BATCH;                           // 64 B
    int* flags    = ncompB + BATCH;                           // 16 images x 32 ints

    hipMemsetAsync(flags, 0, BATCH * 32 * sizeof(int), stream);

    k_mega<<<NSTRIPS, 256, 0, stream>>>((const float4*)in, out,
                                        LA, sizesA, LB, sizesB,
                                        bits1, bits2, bits3,
                                        carryA, carryB, wordrunA, wordrunB,
                                        ncompA, ncompB, flags);
}